// Round 6
// baseline (670.794 us; speedup 1.0000x reference)
//
#include <hip/hip_runtime.h>
#include <math.h>

typedef unsigned short ushort;
typedef __attribute__((ext_vector_type(8))) short short8v;
typedef __attribute__((ext_vector_type(4))) short short4v;
typedef __attribute__((ext_vector_type(4))) float float4v;
typedef __attribute__((ext_vector_type(8))) __bf16 bf16x8;

#define NHEADS 8
#define NPOS 3136
#define MROWS 50176          // 16*3136
#define KDIM 512

__device__ __forceinline__ ushort f2bf(float f) {
  union { float f; unsigned u; } x; x.f = f;
  unsigned r = x.u + 0x7fffu + ((x.u >> 16) & 1u);
  return (ushort)(r >> 16);
}
__device__ __forceinline__ float bf2f(ushort h) {
  union { unsigned u; float f; } x; x.u = ((unsigned)h) << 16; return x.f;
}

__device__ __forceinline__ float4v mfma16(short8v a, short8v b, float4v c) {
  return __builtin_amdgcn_mfma_f32_16x16x32_bf16(
      __builtin_bit_cast(bf16x8, a), __builtin_bit_cast(bf16x8, b), c, 0, 0, 0);
}

__device__ __forceinline__ void glds16(const void* g, void* l) {
  __builtin_amdgcn_global_load_lds(
      (const __attribute__((address_space(1))) unsigned int*)g,
      (__attribute__((address_space(3))) unsigned int*)l, 16, 0, 0);
}

// fast 2^x / log2(x) (single VOP1, ~1 ulp — inputs are bf16-derived)
__device__ __forceinline__ float fexp2(float x) {
  float r; asm("v_exp_f32 %0, %1" : "=v"(r) : "v"(x)); return r;
}
__device__ __forceinline__ float flog2(float x) {
  float r; asm("v_log_f32 %0, %1" : "=v"(r) : "v"(x)); return r;
}

// ---------------- prep: scale_inv, power ----------------
__global__ __launch_bounds__(512) void prep_kernel(const float* __restrict__ scale_p,
                                                   const float* __restrict__ power_p,
                                                   float* __restrict__ scinv,
                                                   float* __restrict__ pwr)
{
  int t = threadIdx.x;
  if (t < KDIM) {
    scinv[t] = 1.f / log1pf(expf(scale_p[t]));
    pwr[t]   = 1.f + 4.f / (1.f + expf(-power_p[t]));
  }
}

// ---------------- x fp32 -> bf16 ----------------
__global__ __launch_bounds__(256) void cvt_x_kernel(const float* __restrict__ x,
                                                    ushort* __restrict__ xb)
{
  const size_t i = ((size_t)blockIdx.x * 256 + threadIdx.x) * 4;
  float4v v = *(const float4v*)(x + i);
  short4v o = { (short)f2bf(v[0]), (short)f2bf(v[1]), (short)f2bf(v[2]), (short)f2bf(v[3]) };
  *(short4v*)(xb + i) = o;
}

// ---------------- weight transpose fp32[K][N] -> bf16[N][K] ----------------
__global__ __launch_bounds__(256) void transpose_w_kernel(const float* __restrict__ src,
                                                          ushort* __restrict__ dst,
                                                          int K, int N)
{
  __shared__ float tile[32][33];
  const int t = threadIdx.x, tx = t & 31, ty = t >> 5;
  const int nb = blockIdx.x * 32, kb = blockIdx.y * 32;
  #pragma unroll
  for (int i = 0; i < 4; i++)
    tile[ty + i*8][tx] = src[(size_t)(kb + ty + i*8) * N + nb + tx];
  __syncthreads();
  #pragma unroll
  for (int i = 0; i < 4; i++)
    dst[(size_t)(nb + ty + i*8) * K + kb + tx] = f2bf(tile[tx][ty + i*8]);
}

// ---------------- pos_enc transpose fp32[3136][512] -> fp32[512][3136] -------
__global__ __launch_bounds__(256) void transpose_pe_kernel(const float* __restrict__ src,
                                                           float* __restrict__ dst)
{
  __shared__ float tile[32][33];
  const int t = threadIdx.x, tx = t & 31, ty = t >> 5;
  const int nb = blockIdx.x * 32, kb = blockIdx.y * 32;   // nb over 512, kb over 3136
  #pragma unroll
  for (int i = 0; i < 4; i++)
    tile[ty + i*8][tx] = src[(size_t)(kb + ty + i*8) * 512 + nb + tx];
  __syncthreads();
  #pragma unroll
  for (int i = 0; i < 4; i++)
    dst[(size_t)(nb + ty + i*8) * NPOS + kb + tx] = tile[tx][ty + i*8];
}

// ------- bf16 MFMA GEMM 256x128xK512, 64x64 wave tiles, ring-3 vmcnt -------
// A bf16 [M][512]; Bt bf16 [N][512]. C[m][n] = sum_k A[m][k]*Bt[n][k]
// 8 waves (4M x 2N), wave tile 64x64, acc = 64 f32/thread. BK=32, 16 iters.
// Per wave-iter: 8 ds_read_b128 feed 16 MFMA (port:MFMA ~1.2 vs 2.4 at 64x32).
// LDS ring of 3 stages (A 16KB + B 8KB) = 72 KiB -> 2 blocks/CU (4 waves/SIMD).
// Prefetch distance 2 via counted s_waitcnt vmcnt(3) — 3 glds/thread/stage.
// Chunk-XOR swizzle: row R, phys chunk = logical ^ (R&3) ^ ((R>>2)&3).
__global__ __launch_bounds__(512, 4) void gemm_bf16_kernel(
    const ushort* __restrict__ A, const ushort* __restrict__ Bt, int mode,
    const float* __restrict__ scinv, const float* __restrict__ pwr,
    const float* __restrict__ pos_enc, const float* __restrict__ bias,
    float* __restrict__ outf, ushort* __restrict__ outb0, ushort* __restrict__ outb1,
    int nbx_shift)
{
  __shared__ ushort As[3][256*32];   // 3 x 16 KiB
  __shared__ ushort Bs[3][128*32];   // 3 x 8 KiB
  const int t = threadIdx.x;
  const int wave = t >> 6, lane = t & 63;

  // bijective chunked XCD swizzle (nwg divisible by 8)
  const int nwg = (int)(gridDim.x * gridDim.y);
  const int lid = (int)(blockIdx.y * gridDim.x + blockIdx.x);
  const int nlid = (lid & 7) * (nwg >> 3) + (lid >> 3);
  const int bx = nlid & ((1 << nbx_shift) - 1);
  const int by = nlid >> nbx_shift;
  const int m0 = ((mode == 3) ? bx : by) * 256;
  const int n0 = ((mode == 3) ? by : bx) * 128;

  const int wm = wave >> 1, wn = wave & 1;      // wave tile: 64 rows x 64 cols
  const int lm = lane & 15, q = lane >> 4;

  // ---- staging addressing: thread t -> row t>>2, phys chunk t&3 ----
  const int srow = t >> 2;
  const int lc = ((t & 3) ^ (srow & 3) ^ ((srow >> 2) & 3)) * 8;  // logical chunk (shorts)
  const ushort* gA = A  + (size_t)(m0 + srow) * KDIM + lc;        // rows 0..127; +128 same swz
  const ushort* gB = Bt + (size_t)(n0 + srow) * KDIM + lc;
  const size_t A128 = (size_t)128 * KDIM;

  // ---- read addressing: phys chunk = q ^ (lm&3) ^ ((lm>>2)&3) ----
  const int pc = (q ^ (lm & 3) ^ ((lm >> 2) & 3)) * 8;
  const int arow = wm * 64 + lm;
  const int brow = wn * 64 + lm;

  float4v acc[4][4];
  #pragma unroll
  for (int i = 0; i < 4; i++)
    #pragma unroll
    for (int j = 0; j < 4; j++) { float4v z = {0.f,0.f,0.f,0.f}; acc[i][j] = z; }

  // prologue: stage tiles 0 and 1 (A-lo, A-hi, B per stage)
  glds16(gA,              &As[0][t*8]);
  glds16(gA + A128,       &As[0][t*8 + 4096]);
  glds16(gB,              &Bs[0][t*8]);
  glds16(gA + 32,         &As[1][t*8]);
  glds16(gA + A128 + 32,  &As[1][t*8 + 4096]);
  glds16(gB + 32,         &Bs[1][t*8]);

  #pragma unroll
  for (int kt = 0; kt < 16; kt++) {
    // wait for stage kt (3 newer glds of stage kt+1 may stay in flight)
    if (kt < 15) asm volatile("s_waitcnt vmcnt(3)" ::: "memory");
    else         asm volatile("s_waitcnt vmcnt(0)" ::: "memory");
    __builtin_amdgcn_sched_barrier(0);
    __builtin_amdgcn_s_barrier();
    if (kt + 2 < 16) {
      const int nb = (kt + 2) % 3;   // == buf of stage kt-1: reads done pre-barrier
      const int off = (kt + 2) * 32;
      glds16(gA + off,        &As[nb][t*8]);
      glds16(gA + A128 + off, &As[nb][t*8 + 4096]);
      glds16(gB + off,        &Bs[nb][t*8]);
    }
    const int cb = kt % 3;
    short8v a[4], b[4];
    #pragma unroll
    for (int i = 0; i < 4; i++)
      a[i] = *(const short8v*)&As[cb][(arow + i*16) * 32 + pc];
    #pragma unroll
    for (int j = 0; j < 4; j++)
      b[j] = *(const short8v*)&Bs[cb][(brow + j*16) * 32 + pc];
    #pragma unroll
    for (int i = 0; i < 4; i++)
      #pragma unroll
      for (int j = 0; j < 4; j++)
        acc[i][j] = mfma16(a[i], b[j], acc[i][j]);
  }

  // ---------------- epilogue ----------------
  const int rq = (lane >> 4) * 4;
  if (mode == 3) {
    #pragma unroll
    for (int i = 0; i < 4; i++) {
      const int of0 = m0 + wm * 64 + i * 16 + rq;
      #pragma unroll
      for (int j = 0; j < 4; j++) {
        const int gn = n0 + wn * 64 + j * 16;   // 16-aligned; 3136%16==0 -> no straddle
        const int bb = gn / NPOS;
        const int nn = gn - bb * NPOS + lm;
        #pragma unroll
        for (int r = 0; r < 4; r++) {
          const int o = of0 + r;
          const float val = acc[i][j][r];
          if (o < 512) {
            const int h = o >> 6, d = o & 63;
            const float sv = (val + pos_enc[(size_t)o * NPOS + nn]) * scinv[o];
            const float pw = pwr[o];
            const float aq = fabsf(sv);
            const float f = fexp2(pw * flog2(aq));   // aq=0 -> 0
            const ushort fb = f2bf(f);
            ushort* kr = outb0 + ((size_t)((bb << 3) + h) * 128 + 2 * d) * NPOS + nn;
            kr[0]    = (sv > 0.f) ? fb : (ushort)0;
            kr[NPOS] = (sv < 0.f) ? fb : (ushort)0;
          } else {
            const int ov = o - 512;
            const int h = ov >> 6, e = ov & 63;
            outb1[((size_t)((bb << 3) + h) * 64 + e) * NPOS + nn] = f2bf(val);
          }
        }
      }
    }
  } else {
    #pragma unroll
    for (int i = 0; i < 4; i++) {
      #pragma unroll
      for (int r = 0; r < 4; r++) {
        const int grow = m0 + wm * 64 + i * 16 + rq + r;
        const int bb = grow / NPOS;
        const int nn = grow - bb * NPOS;
        #pragma unroll
        for (int j = 0; j < 4; j++) {
          const int gcol = n0 + wn * 64 + j * 16 + lm;
          const float val = acc[i][j][r];
          if (mode == 2) {
            outf[(size_t)grow * 512 + gcol] = val + bias[gcol];
          } else if (gcol < 512) {
            const float sv = val * scinv[gcol];
            const float pw = pwr[gcol];
            const float aq = fabsf(sv);
            const float f = fexp2(pw * flog2(aq));
            const unsigned fb = (unsigned)f2bf(f);
            unsigned pack = 0;
            if (sv > 0.f)      pack = fb;
            else if (sv < 0.f) pack = fb << 16;
            const int h = gcol >> 6, d = gcol & 63;
            unsigned* qrow = (unsigned*)(outb0 + (((size_t)((bb << 3) + h) * NPOS + nn) << 7));
            qrow[d] = pack;   // features interleaved: f=2d (pos), 2d+1 (neg)
          } else {
            const int c2 = gcol - 512;
            outb1[(size_t)grow * 512 + c2] = f2bf(val);        // g bf16 natural
          }
        }
      }
    }
  }
}

// ------- kv reduce as MFMA GEMM: pkv[sp][bh][128f][64e] = KFt·Vt^T ---------
// A = KFt [bh][128f][3136], B = Vt [bh][64e][3136], contraction over n.
// Per block: M=128, N=64, K=448 (RSPLIT=7). 4 waves (2x2), wave tile 64x32.
// km (row-sums of KFt) via constant ones-column B fragment -> pkm.
#define RSPLIT 7
#define RK 448
__global__ __launch_bounds__(256, 4) void reduce_kv_kernel(
    const ushort* __restrict__ KFt, const ushort* __restrict__ Vt,
    float* __restrict__ pkv, float* __restrict__ pkm)
{
  __shared__ ushort As[3][128*32];   // 3 x 8 KiB
  __shared__ ushort Bs[3][64*32];    // 3 x 4 KiB
  const int sp = blockIdx.x, bh = blockIdx.y;
  const int t = threadIdx.x;
  const int wave = t >> 6, lane = t & 63;
  const int wm = wave >> 1, wn = wave & 1;
  const int lm = lane & 15, q = lane >> 4;

  const int r0 = t >> 2;
  const int lc = ((t & 3) ^ (r0 & 3) ^ ((r0 >> 2) & 3)) * 8;
  const ushort* gA = KFt + ((size_t)bh * 128 + r0) * NPOS + sp * RK + lc;  // rows 0..63 (+64 via offset)
  const ushort* gB = Vt  + ((size_t)bh * 64  + r0) * NPOS + sp * RK + lc;
  const size_t A64 = (size_t)64 * NPOS;   // swizzle identical for row+64

  const int pc = (q ^ (lm & 3) ^ ((lm >> 2) & 3)) * 8;
  const int arow = wm * 64 + lm;
  const int brow = wn * 32 + lm;

  float4v acc[4][2], accK[4];
  #pragma unroll
  for (int i = 0; i < 4; i++) {
    #pragma unroll
    for (int j = 0; j < 2; j++) { float4v z = {0.f,0.f,0.f,0.f}; acc[i][j] = z; }
    float4v z = {0.f,0.f,0.f,0.f}; accK[i] = z;
  }
  short8v bk;
  #pragma unroll
  for (int c = 0; c < 8; c++) bk[c] = (short)((lm == 0) ? 0x3F80 : 0);

  // prologue: stage tiles 0 and 1
  glds16(gA,            &As[0][t*8]);
  glds16(gA + A64,      &As[0][2048 + t*8]);
  glds16(gB,            &Bs[0][t*8]);
  glds16(gA + 32,       &As[1][t*8]);
  glds16(gA + A64 + 32, &As[1][2048 + t*8]);
  glds16(gB + 32,       &Bs[1][t*8]);

  #pragma unroll
  for (int kt = 0; kt < 14; kt++) {
    if (kt < 13) asm volatile("s_waitcnt vmcnt(3)" ::: "memory");
    else         asm volatile("s_waitcnt vmcnt(0)" ::: "memory");
    __builtin_amdgcn_sched_barrier(0);
    __builtin_amdgcn_s_barrier();
    if (kt + 2 < 14) {
      const int nb = (kt + 2) % 3;
      const int off = (kt + 2) * 32;
      glds16(gA + off,       &As[nb][t*8]);
      glds16(gA + A64 + off, &As[nb][2048 + t*8]);
      glds16(gB + off,       &Bs[nb][t*8]);
    }
    const int cb = kt % 3;
    short8v a[4], b[2];
    #pragma unroll
    for (int i = 0; i < 4; i++)
      a[i] = *(const short8v*)&As[cb][(arow + i*16) * 32 + pc];
    #pragma unroll
    for (int j = 0; j < 2; j++)
      b[j] = *(const short8v*)&Bs[cb][(brow + j*16) * 32 + pc];
    #pragma unroll
    for (int i = 0; i < 4; i++)
      #pragma unroll
      for (int j = 0; j < 2; j++)
        acc[i][j] = mfma16(a[i], b[j], acc[i][j]);
    if (wn == 0) {
      #pragma unroll
      for (int i = 0; i < 4; i++)
        accK[i] = mfma16(a[i], bk, accK[i]);
    }
  }

  const int rq = q * 4;
  float* op = pkv + (((size_t)sp * 128 + bh) << 13);
  #pragma unroll
  for (int i = 0; i < 4; i++)
    #pragma unroll
    for (int j = 0; j < 2; j++)
      #pragma unroll
      for (int r = 0; r < 4; r++)
        op[(size_t)(wm*64 + i*16 + rq + r) * 64 + wn*32 + j*16 + lm] = acc[i][j][r];
  if (wn == 0 && lm == 0) {
    float* kp = pkm + (((size_t)sp * 128 + bh) << 7);
    #pragma unroll
    for (int i = 0; i < 4; i++)
      #pragma unroll
      for (int r = 0; r < 4; r++)
        kp[wm*64 + i*16 + rq + r] = accK[i][r];
  }
}

// ---------------- final reduce -> kvf2^T bf16 [bh][80][128] ----------------
__global__ __launch_bounds__(256) void reduce_final_kernel(
    const float* __restrict__ pkv, const float* __restrict__ pkm,
    ushort* __restrict__ Kt)
{
  const int bh = blockIdx.x, t = threadIdx.x;
  const float inv_n = 1.f / (float)NPOS;
  for (int i = t; i < 8192; i += 256) {
    float s = 0.f;
    #pragma unroll
    for (int sp = 0; sp < RSPLIT; sp++) s += pkv[((size_t)(sp*128 + bh) << 13) + i];
    const int d = i >> 6, e = i & 63;
    const int dd = (e < 32) ? d : (d ^ 1);
    Kt[((size_t)bh*80 + e)*128 + dd] = f2bf(s * inv_n);
  }
  if (t < 128) {
    float s = 0.f;
    #pragma unroll
    for (int sp = 0; sp < RSPLIT; sp++) s += pkm[((size_t)(sp*128 + bh) << 7) + t];
    const ushort b = f2bf(s * inv_n);
    Kt[((size_t)bh*80 + 64)*128 + t] = b;          // km (denom_sim column)
    Kt[((size_t)bh*80 + 65)*128 + (t ^ 1)] = b;    // km swapped (denom_opp)
  }
  for (int i = t; i < 14*128; i += 256) Kt[((size_t)bh*80 + 66)*128 + i] = 0;
}

// ---------------- attention apply: MFMA [128x80] = QS[128x128] @ Kt^T -------
__global__ __launch_bounds__(256) void attn_mfma_kernel(
    const ushort* __restrict__ QS, const ushort* __restrict__ Kt,
    ushort* __restrict__ XO)
{
  __shared__ ushort qs_s[128*128];
  __shared__ ushort kv_s[80*128];
  const int t = threadIdx.x, wave = t >> 6, lane = t & 63;
  const int bh = blockIdx.y;
  const int n0 = blockIdx.x * 128;

  const ushort* ksrc = Kt + (size_t)bh * 80 * 128;
  #pragma unroll
  for (int j = 0; j < 5; j++) {
    const int elem = (j*4096 + wave*1024) >> 1;
    glds16(ksrc + elem + lane*8, kv_s + elem);
  }
  const ushort* qsrc = QS + ((size_t)bh * NPOS + n0) * 128;
  #pragma unroll
  for (int j = 0; j < 8; j++) {
    const int elem = (j*4096 + wave*1024) >> 1;
    glds16(qsrc + elem + lane*8, qs_s + elem);
  }
  __syncthreads();

  const int lm = lane & 15, q8 = (lane >> 4) * 8;
  float4v acc[2][5];
  #pragma unroll
  for (int i = 0; i < 2; i++)
    #pragma unroll
    for (int j = 0; j < 5; j++) { float4v z = {0.f,0.f,0.f,0.f}; acc[i][j] = z; }

  #pragma unroll
  for (int ks = 0; ks < 4; ks++) {
    short8v a[2], b[5];
    #pragma unroll
    for (int i = 0; i < 2; i++)
      a[i] = *(const short8v*)&qs_s[(wave*32 + i*16 + lm)*128 + ks*32 + q8];
    #pragma unroll
    for (int j = 0; j < 5; j++)
      b[j] = *(const short8v*)&kv_s[(j*16 + lm)*128 + ks*32 + q8];
    #pragma unroll
    for (int i = 0; i < 2; i++)
      #pragma unroll
      for (int j = 0; j < 5; j++)
        acc[i][j] = mfma16(a[i], b[j], acc[i][j]);
  }

  const int rq = (lane >> 4) * 4;
  #pragma unroll
  for (int i = 0; i < 2; i++) {
    #pragma unroll
    for (int r = 0; r < 4; r++) {
      const int n = n0 + wave*32 + i*16 + rq + r;
      const float dsim = __shfl(acc[i][4][r], lane & 48);
      const float dopp = __shfl(acc[i][4][r], (lane & 48) | 1);
      const float zs = 1.f / (dsim + 1e-6f);
      const float zo = 1.f / (dopp + 1e-6f);
      if (n < NPOS) {
        ushort* orow = XO + (((size_t)bh * NPOS + n) << 6);
        #pragma unroll
        for (int j = 0; j < 4; j++)
          orow[j*16 + lm] = f2bf(acc[i][j][r] * ((j < 2) ? zs : zo));
      }
    }
  }
}

// ------- 5x5 depthwise conv (Vt image-major, vector staging) + combine -------
__global__ __launch_bounds__(256) void conv_combine_kernel(
    const ushort* __restrict__ Vt, const ushort* __restrict__ XO,
    const ushort* __restrict__ g, const float* __restrict__ dwc_w,
    const float* __restrict__ dwc_b, ushort* __restrict__ cmb)
{
  __shared__ ushort vs[6*60*66];   // 47520 B -> 3 blocks/CU
  const int t = threadIdx.x;
  const int bh = blockIdx.y, b = bh >> 3, h = bh & 7;
  const int y0 = blockIdx.x * 2;

  // zero the x-halo columns xs in {0,1,58,59}
  for (int i = t; i < 6*64*4; i += 256) {
    const int c = i & 63, rem = i >> 6;       // rem 0..23
    const int ry = rem >> 2, hs = rem & 3;
    const int xs = (hs < 2) ? hs : hs + 56;   // 0,1,58,59
    vs[(ry*60 + xs)*66 + c] = 0;
  }
  // octet loads: 6 ry x 64 c x 7 j (j fastest for x-contiguous coalescing)
  for (int i = t; i < 6*64*7; i += 256) {
    const int j = i % 7;
    const int rem = i / 7;
    const int c = rem & 63, ry = rem >> 6;
    const int yy = y0 - 2 + ry;
    const int base = (ry*60 + j*8 + 2)*66 + c;
    if (yy >= 0 && yy < 56) {
      short8v v = *(const short8v*)&Vt[((size_t)bh*64 + c)*NPOS + yy*56 + j*8];
      #pragma unroll
      for (int e = 0; e < 8; e++) vs[base + e*66] = (ushort)v[e];
    } else {
      #pragma unroll
      for (int e = 0; e < 8; e++) vs[base + e*66] = 0;
    }
  }
  __syncthreads();

  const int c = t & 63, xg = t >> 6;   // 4 x-groups of 14
  float w[25];
  #pragma unroll
  for (int i = 0; i < 25; i++) w[i] = dwc_w[c*25 + i];
  const float bias = dwc_b[c];

  float acc[2][14];
  #pragma unroll
  for (int y = 0; y < 2; y++)
    #pragma unroll
    for (int xi = 0; xi < 14; xi++) acc[y][xi] = bias;

  #pragma unroll
  for (int r = 0; r < 6; r++) {
    float rv[18];
    const ushort* row = &vs[(r*60 + xg*14)*66 + c];
    #pragma unroll
    for (int xl = 0; xl < 18; xl++) rv[xl] = bf2f(row[xl*66]);
    #pragma unroll
    for (int y = 0; y < 2; y++) {
      const int ky = r - y;
      if (ky >= 0 && ky < 5) {
        #pragma unroll
        for (int xl = 0; xl < 18; xl++) {
          #pragma unroll
          for (int kx = 0; kx < 5; kx++) {
            const int xi = xl - kx;
            if (xi >= 0 && xi < 14)
              acc[y][xi] = fmaf(w[ky*5 + kx], rv[xl], acc[y][xi]);
          }
        }
      }
    }
  }

  #pragma unroll
  for (int y = 0; y < 2; y++) {
    const int yo = y0 + y;
    #pragma unroll
    for (int xi = 0; xi < 14; xi++) {
      const int n = yo*56 + xg*14 + xi;
      const float xov = bf2f(XO[(((size_t)bh*NPOS + n) << 6) + c]);
      const size_t nat = ((size_t)b*NPOS + n)*512 + h*64 + c;
      cmb[nat] = f2bf((xov + acc[y][xi]) * bf2f(g[nat]));
    }
  }
}

// ---------------- launch ----------------
extern "C" void kernel_launch(void* const* d_in, const int* in_sizes, int n_in,
                              void* d_out, int out_size, void* d_ws, size_t ws_size,
                              hipStream_t stream)
{
  const float* x       = (const float*)d_in[0];
  const float* qg_w    = (const float*)d_in[1];
  const float* kv_w    = (const float*)d_in[2];
  const float* proj_w  = (const float*)d_in[3];
  const float* proj_b  = (const float*)d_in[4];
  const float* pos_enc = (const float*)d_in[5];
  const float* scale_p = (const float*)d_in[6];
  const float* power_p = (const float*)d_in[7];
  const float* dwc_w   = (const float*)d_in[8];
  const float* dwc_b   = (const float*)d_in[9];
  float* out = (float*)d_out;

  const size_t MCs = (size_t)MROWS * 512;        // 25,690,112
  ushort* xbf = (ushort*)d_ws;                   // x bf16 -> later XO bf16 head-major
  ushort* KQ  = xbf + MCs;                       // KFt [128][128][3136] -> QS -> cmb
  ushort* Vt  = KQ + 2*MCs + 8192;               // v^T bf16 [128bh][64e][3136]
  ushort* Kt  = Vt + MCs;                        // kvf2^T bf16 [128][80][128]
  ushort* wqg = Kt + (size_t)128*80*128;         // qg_w^T bf16 [1024][512]
  ushort* wkv = wqg + (size_t)1024*512;
  ushort* wpj = wkv + (size_t)1024*512;          // proj_w^T bf16 [512][512]
  float* pkv  = (float*)(wpj + (size_t)512*512); // 7*128*8192
  float* pkm  = pkv + (size_t)RSPLIT*128*8192;   // 7*128*128
  float* scinv= pkm + (size_t)RSPLIT*128*128;
  float* pwr  = scinv + 512;
  const size_t need = (size_t)((char*)(pwr + 512) - (char*)d_ws);
  if (ws_size < need) return;

  ushort* XOb = xbf;          // aliases x_bf (dead after qg GEMM)
  ushort* cmb = KQ;           // aliases QS (dead after attn)
  ushort* gbuf = (ushort*)out;// g bf16 in d_out low half (consumed before proj overwrites)
  float* peT = (float*)d_out + 13000000;  // pos_enc^T fp32 [512][3136] scratch
                                          // (d_out = 25.69M f32; gbuf = first 12.85M f32)

  prep_kernel<<<1, 512, 0, stream>>>(scale_p, power_p, scinv, pwr);
  cvt_x_kernel<<<(int)(MCs/4/256), 256, 0, stream>>>(x, xbf);
  transpose_w_kernel<<<dim3(32,16), 256, 0, stream>>>(qg_w,   wqg, 512, 1024);
  transpose_w_kernel<<<dim3(32,16), 256, 0, stream>>>(kv_w,   wkv, 512, 1024);
  transpose_w_kernel<<<dim3(16,16), 256, 0, stream>>>(proj_w, wpj, 512, 512);
  transpose_pe_kernel<<<dim3(16,98), 256, 0, stream>>>(pos_enc, peT);

  // kv GEMM, transposed orientation: A=wkv (M=1024 -> 4 blocks of 256),
  // B=xbf (N'=50176 -> 392 blocks of 128); grid 4x392, nbx_shift=2
  gemm_bf16_kernel<<<dim3(4, MROWS/128), 512, 0, stream>>>(
      wkv, xbf, 3, scinv, pwr, peT, nullptr, nullptr, KQ, Vt, 2);
  reduce_kv_kernel<<<dim3(RSPLIT, 128), 256, 0, stream>>>(KQ, Vt, pkv, pkm);
  reduce_final_kernel<<<128, 256, 0, stream>>>(pkv, pkm, Kt);
  // qg GEMM: A=xbf (M=50176 -> 196 blocks of 256), B=wqg (1024 -> 8 of 128)
  gemm_bf16_kernel<<<dim3(8, MROWS/256), 512, 0, stream>>>(
      xbf, wqg, 0, scinv, pwr, nullptr, nullptr, nullptr, KQ, gbuf, 3);
  attn_mfma_kernel<<<dim3(25, 128), 256, 0, stream>>>(KQ, Kt, XOb);
  conv_combine_kernel<<<dim3(28, 128), 256, 0, stream>>>(Vt, XOb, gbuf, dwc_w, dwc_b, cmb);
  // proj GEMM: A=cmb (196 blocks of 256), B=wpj (512 -> 4 of 128)
  gemm_bf16_kernel<<<dim3(4, MROWS/256), 512, 0, stream>>>(
      cmb, wpj, 2, nullptr, nullptr, nullptr, proj_b, out, nullptr, nullptr, 2);
}

// Round 7
// 636.253 us; speedup vs baseline: 1.0543x; 1.0543x over previous
//
#include <hip/hip_runtime.h>
#include <math.h>

typedef unsigned short ushort;
typedef __attribute__((ext_vector_type(8))) short short8v;
typedef __attribute__((ext_vector_type(4))) short short4v;
typedef __attribute__((ext_vector_type(4))) float float4v;
typedef __attribute__((ext_vector_type(8))) __bf16 bf16x8;

#define NHEADS 8
#define NPOS 3136
#define MROWS 50176          // 16*3136
#define KDIM 512

__device__ __forceinline__ ushort f2bf(float f) {
  union { float f; unsigned u; } x; x.f = f;
  unsigned r = x.u + 0x7fffu + ((x.u >> 16) & 1u);
  return (ushort)(r >> 16);
}
__device__ __forceinline__ float bf2f(ushort h) {
  union { unsigned u; float f; } x; x.u = ((unsigned)h) << 16; return x.f;
}

__device__ __forceinline__ float4v mfma16(short8v a, short8v b, float4v c) {
  return __builtin_amdgcn_mfma_f32_16x16x32_bf16(
      __builtin_bit_cast(bf16x8, a), __builtin_bit_cast(bf16x8, b), c, 0, 0, 0);
}

__device__ __forceinline__ void glds16(const void* g, void* l) {
  __builtin_amdgcn_global_load_lds(
      (const __attribute__((address_space(1))) unsigned int*)g,
      (__attribute__((address_space(3))) unsigned int*)l, 16, 0, 0);
}

// fast 2^x / log2(x) (single VOP1, ~1 ulp — inputs are bf16-derived)
__device__ __forceinline__ float fexp2(float x) {
  float r; asm("v_exp_f32 %0, %1" : "=v"(r) : "v"(x)); return r;
}
__device__ __forceinline__ float flog2(float x) {
  float r; asm("v_log_f32 %0, %1" : "=v"(r) : "v"(x)); return r;
}

// ---------------- prep: scale_inv, power ----------------
__global__ __launch_bounds__(512) void prep_kernel(const float* __restrict__ scale_p,
                                                   const float* __restrict__ power_p,
                                                   float* __restrict__ scinv,
                                                   float* __restrict__ pwr)
{
  int t = threadIdx.x;
  if (t < KDIM) {
    scinv[t] = 1.f / log1pf(expf(scale_p[t]));
    pwr[t]   = 1.f + 4.f / (1.f + expf(-power_p[t]));
  }
}

// ---------------- x fp32 -> bf16 ----------------
__global__ __launch_bounds__(256) void cvt_x_kernel(const float* __restrict__ x,
                                                    ushort* __restrict__ xb)
{
  const size_t i = ((size_t)blockIdx.x * 256 + threadIdx.x) * 4;
  float4v v = *(const float4v*)(x + i);
  short4v o = { (short)f2bf(v[0]), (short)f2bf(v[1]), (short)f2bf(v[2]), (short)f2bf(v[3]) };
  *(short4v*)(xb + i) = o;
}

// ---------------- weight transpose fp32[K][N] -> bf16[N][K] ----------------
__global__ __launch_bounds__(256) void transpose_w_kernel(const float* __restrict__ src,
                                                          ushort* __restrict__ dst,
                                                          int K, int N)
{
  __shared__ float tile[32][33];
  const int t = threadIdx.x, tx = t & 31, ty = t >> 5;
  const int nb = blockIdx.x * 32, kb = blockIdx.y * 32;
  #pragma unroll
  for (int i = 0; i < 4; i++)
    tile[ty + i*8][tx] = src[(size_t)(kb + ty + i*8) * N + nb + tx];
  __syncthreads();
  #pragma unroll
  for (int i = 0; i < 4; i++)
    dst[(size_t)(nb + ty + i*8) * K + kb + tx] = f2bf(tile[tx][ty + i*8]);
}

// ---------------- pos_enc transpose fp32[3136][512] -> fp32[512][3136] -------
__global__ __launch_bounds__(256) void transpose_pe_kernel(const float* __restrict__ src,
                                                           float* __restrict__ dst)
{
  __shared__ float tile[32][33];
  const int t = threadIdx.x, tx = t & 31, ty = t >> 5;
  const int nb = blockIdx.x * 32, kb = blockIdx.y * 32;   // nb over 512, kb over 3136
  #pragma unroll
  for (int i = 0; i < 4; i++)
    tile[ty + i*8][tx] = src[(size_t)(kb + ty + i*8) * 512 + nb + tx];
  __syncthreads();
  #pragma unroll
  for (int i = 0; i < 4; i++)
    dst[(size_t)(nb + ty + i*8) * NPOS + kb + tx] = tile[tx][ty + i*8];
}

// ------- bf16 MFMA GEMM 128x128xK512, 3-deep ring + counted vmcnt -------
// REVERTED to the round-5 configuration (proven fastest: 125 us/feature GEMM):
// 8 waves (2M x 4N), wave tile 64x32, BK=32, ring-3 = 48 KiB -> 3 blocks/CU,
// prefetch distance 2 via counted s_waitcnt vmcnt(2). + T5 setprio on MFMA.
// mode 0: qg (A=xbf, Bt=wqg): QS interleaved features + g natural
// mode 2: proj: natural fp32 + bias
// mode 3: kv TRANSPOSED orientation (A=wkv, Bt=xbf): KFt [bh][128f][3136]
//         (f=2d+neg) and Vt [bh][64e][3136]; pos_enc arg = peT fp32 [512][3136].
__global__ __launch_bounds__(512, 6) void gemm_bf16_kernel(
    const ushort* __restrict__ A, const ushort* __restrict__ Bt, int mode,
    const float* __restrict__ scinv, const float* __restrict__ pwr,
    const float* __restrict__ pos_enc, const float* __restrict__ bias,
    float* __restrict__ outf, ushort* __restrict__ outb0, ushort* __restrict__ outb1,
    int nbx_shift)
{
  __shared__ ushort As[3][128*32];   // 3 x 8 KiB
  __shared__ ushort Bs[3][128*32];   // 3 x 8 KiB
  const int t = threadIdx.x;
  const int wave = t >> 6, lane = t & 63;

  // bijective chunked XCD swizzle (nwg divisible by 8)
  const int nwg = (int)(gridDim.x * gridDim.y);
  const int lid = (int)(blockIdx.y * gridDim.x + blockIdx.x);
  const int nlid = (lid & 7) * (nwg >> 3) + (lid >> 3);
  const int bx = nlid & ((1 << nbx_shift) - 1);
  const int by = nlid >> nbx_shift;
  const int m0 = ((mode == 3) ? bx : by) * 128;
  const int n0 = ((mode == 3) ? by : bx) * 128;

  const int wm = wave >> 2, wn = wave & 3;      // wave tile: 64 rows x 32 cols
  const int lm = lane & 15, q = lane >> 4;

  // ---- staging addressing: thread t -> row t>>2, phys chunk t&3 ----
  const int srow = t >> 2;
  const int lc = ((t & 3) ^ (srow & 3) ^ ((srow >> 2) & 3)) * 8;  // logical chunk (shorts)
  const ushort* gA = A  + (size_t)(m0 + srow) * KDIM + lc;
  const ushort* gB = Bt + (size_t)(n0 + srow) * KDIM + lc;

  // ---- read addressing: phys chunk = q ^ (lm&3) ^ ((lm>>2)&3) ----
  const int pc = (q ^ (lm & 3) ^ ((lm >> 2) & 3)) * 8;
  const int arow = wm * 64 + lm;
  const int brow = wn * 32 + lm;

  float4v acc[4][2];
  #pragma unroll
  for (int i = 0; i < 4; i++)
    #pragma unroll
    for (int j = 0; j < 2; j++) { float4v z = {0.f,0.f,0.f,0.f}; acc[i][j] = z; }

  // prologue: stage tiles 0 and 1
  glds16(gA,      &As[0][t*8]);
  glds16(gB,      &Bs[0][t*8]);
  glds16(gA + 32, &As[1][t*8]);
  glds16(gB + 32, &Bs[1][t*8]);

  #pragma unroll
  for (int kt = 0; kt < 16; kt++) {
    // wait for stage kt (2 newer glds of stage kt+1 may stay in flight)
    if (kt < 15) asm volatile("s_waitcnt vmcnt(2)" ::: "memory");
    else         asm volatile("s_waitcnt vmcnt(0)" ::: "memory");
    __builtin_amdgcn_sched_barrier(0);
    __builtin_amdgcn_s_barrier();
    if (kt + 2 < 16) {
      const int nb = (kt + 2) % 3;   // == buf of stage kt-1: reads done pre-barrier
      glds16(gA + (kt + 2) * 32, &As[nb][t*8]);
      glds16(gB + (kt + 2) * 32, &Bs[nb][t*8]);
    }
    const int cb = kt % 3;
    short8v a[4], b[2];
    #pragma unroll
    for (int i = 0; i < 4; i++)
      a[i] = *(const short8v*)&As[cb][(arow + i*16) * 32 + pc];
    #pragma unroll
    for (int j = 0; j < 2; j++)
      b[j] = *(const short8v*)&Bs[cb][(brow + j*16) * 32 + pc];
    __builtin_amdgcn_s_setprio(1);
    #pragma unroll
    for (int i = 0; i < 4; i++)
      #pragma unroll
      for (int j = 0; j < 2; j++)
        acc[i][j] = mfma16(a[i], b[j], acc[i][j]);
    __builtin_amdgcn_s_setprio(0);
  }

  // ---------------- epilogue ----------------
  const int rq = (lane >> 4) * 4;
  if (mode == 3) {
    #pragma unroll
    for (int i = 0; i < 4; i++) {
      const int of0 = m0 + wm * 64 + i * 16 + rq;
      #pragma unroll
      for (int j = 0; j < 2; j++) {
        const int gn = n0 + wn * 32 + j * 16;   // 16-aligned; 3136%16==0 -> no straddle
        const int bb = gn / NPOS;
        const int nn = gn - bb * NPOS + lm;
        #pragma unroll
        for (int r = 0; r < 4; r++) {
          const int o = of0 + r;
          const float val = acc[i][j][r];
          if (o < 512) {
            const int h = o >> 6, d = o & 63;
            const float sv = (val + pos_enc[(size_t)o * NPOS + nn]) * scinv[o];
            const float pw = pwr[o];
            const float aq = fabsf(sv);
            const float f = fexp2(pw * flog2(aq));   // aq=0 -> 0
            const ushort fb = f2bf(f);
            ushort* kr = outb0 + ((size_t)((bb << 3) + h) * 128 + 2 * d) * NPOS + nn;
            kr[0]    = (sv > 0.f) ? fb : (ushort)0;
            kr[NPOS] = (sv < 0.f) ? fb : (ushort)0;
          } else {
            const int ov = o - 512;
            const int h = ov >> 6, e = ov & 63;
            outb1[((size_t)((bb << 3) + h) * 64 + e) * NPOS + nn] = f2bf(val);
          }
        }
      }
    }
  } else {
    #pragma unroll
    for (int i = 0; i < 4; i++) {
      #pragma unroll
      for (int r = 0; r < 4; r++) {
        const int grow = m0 + wm * 64 + i * 16 + rq + r;
        const int bb = grow / NPOS;
        const int nn = grow - bb * NPOS;
        #pragma unroll
        for (int j = 0; j < 2; j++) {
          const int gcol = n0 + wn * 32 + j * 16 + lm;
          const float val = acc[i][j][r];
          if (mode == 2) {
            outf[(size_t)grow * 512 + gcol] = val + bias[gcol];
          } else if (gcol < 512) {
            const float sv = val * scinv[gcol];
            const float pw = pwr[gcol];
            const float aq = fabsf(sv);
            const float f = fexp2(pw * flog2(aq));
            const unsigned fb = (unsigned)f2bf(f);
            unsigned pack = 0;
            if (sv > 0.f)      pack = fb;
            else if (sv < 0.f) pack = fb << 16;
            const int h = gcol >> 6, d = gcol & 63;
            unsigned* qrow = (unsigned*)(outb0 + (((size_t)((bb << 3) + h) * NPOS + nn) << 7));
            qrow[d] = pack;   // features interleaved: f=2d (pos), 2d+1 (neg)
          } else {
            const int c2 = gcol - 512;
            outb1[(size_t)grow * 512 + c2] = f2bf(val);        // g bf16 natural
          }
        }
      }
    }
  }
}

// ------- kv reduce as MFMA GEMM: pkv[sp][bh][128f][64e] = KFt·Vt^T ---------
// A = KFt [bh][128f][3136], B = Vt [bh][64e][3136], contraction over n.
// Per block: M=128, N=64, K=448 (RSPLIT=7). 4 waves (2x2), wave tile 64x32.
// km (row-sums of KFt) via constant ones-column B fragment -> pkm.
#define RSPLIT 7
#define RK 448
__global__ __launch_bounds__(256, 4) void reduce_kv_kernel(
    const ushort* __restrict__ KFt, const ushort* __restrict__ Vt,
    float* __restrict__ pkv, float* __restrict__ pkm)
{
  __shared__ ushort As[3][128*32];   // 3 x 8 KiB
  __shared__ ushort Bs[3][64*32];    // 3 x 4 KiB
  const int sp = blockIdx.x, bh = blockIdx.y;
  const int t = threadIdx.x;
  const int wave = t >> 6, lane = t & 63;
  const int wm = wave >> 1, wn = wave & 1;
  const int lm = lane & 15, q = lane >> 4;

  const int r0 = t >> 2;
  const int lc = ((t & 3) ^ (r0 & 3) ^ ((r0 >> 2) & 3)) * 8;
  const ushort* gA = KFt + ((size_t)bh * 128 + r0) * NPOS + sp * RK + lc;  // rows 0..63 (+64 via offset)
  const ushort* gB = Vt  + ((size_t)bh * 64  + r0) * NPOS + sp * RK + lc;
  const size_t A64 = (size_t)64 * NPOS;   // swizzle identical for row+64

  const int pc = (q ^ (lm & 3) ^ ((lm >> 2) & 3)) * 8;
  const int arow = wm * 64 + lm;
  const int brow = wn * 32 + lm;

  float4v acc[4][2], accK[4];
  #pragma unroll
  for (int i = 0; i < 4; i++) {
    #pragma unroll
    for (int j = 0; j < 2; j++) { float4v z = {0.f,0.f,0.f,0.f}; acc[i][j] = z; }
    float4v z = {0.f,0.f,0.f,0.f}; accK[i] = z;
  }
  short8v bk;
  #pragma unroll
  for (int c = 0; c < 8; c++) bk[c] = (short)((lm == 0) ? 0x3F80 : 0);

  // prologue: stage tiles 0 and 1
  glds16(gA,            &As[0][t*8]);
  glds16(gA + A64,      &As[0][2048 + t*8]);
  glds16(gB,            &Bs[0][t*8]);
  glds16(gA + 32,       &As[1][t*8]);
  glds16(gA + A64 + 32, &As[1][2048 + t*8]);
  glds16(gB + 32,       &Bs[1][t*8]);

  #pragma unroll
  for (int kt = 0; kt < 14; kt++) {
    if (kt < 13) asm volatile("s_waitcnt vmcnt(3)" ::: "memory");
    else         asm volatile("s_waitcnt vmcnt(0)" ::: "memory");
    __builtin_amdgcn_sched_barrier(0);
    __builtin_amdgcn_s_barrier();
    if (kt + 2 < 14) {
      const int nb = (kt + 2) % 3;
      const int off = (kt + 2) * 32;
      glds16(gA + off,       &As[nb][t*8]);
      glds16(gA + A64 + off, &As[nb][2048 + t*8]);
      glds16(gB + off,       &Bs[nb][t*8]);
    }
    const int cb = kt % 3;
    short8v a[4], b[2];
    #pragma unroll
    for (int i = 0; i < 4; i++)
      a[i] = *(const short8v*)&As[cb][(arow + i*16) * 32 + pc];
    #pragma unroll
    for (int j = 0; j < 2; j++)
      b[j] = *(const short8v*)&Bs[cb][(brow + j*16) * 32 + pc];
    __builtin_amdgcn_s_setprio(1);
    #pragma unroll
    for (int i = 0; i < 4; i++)
      #pragma unroll
      for (int j = 0; j < 2; j++)
        acc[i][j] = mfma16(a[i], b[j], acc[i][j]);
    if (wn == 0) {
      #pragma unroll
      for (int i = 0; i < 4; i++)
        accK[i] = mfma16(a[i], bk, accK[i]);
    }
    __builtin_amdgcn_s_setprio(0);
  }

  const int rq = q * 4;
  float* op = pkv + (((size_t)sp * 128 + bh) << 13);
  #pragma unroll
  for (int i = 0; i < 4; i++)
    #pragma unroll
    for (int j = 0; j < 2; j++)
      #pragma unroll
      for (int r = 0; r < 4; r++)
        op[(size_t)(wm*64 + i*16 + rq + r) * 64 + wn*32 + j*16 + lm] = acc[i][j][r];
  if (wn == 0 && lm == 0) {
    float* kp = pkm + (((size_t)sp * 128 + bh) << 7);
    #pragma unroll
    for (int i = 0; i < 4; i++)
      #pragma unroll
      for (int r = 0; r < 4; r++)
        kp[wm*64 + i*16 + rq + r] = accK[i][r];
  }
}

// ---------------- final reduce -> kvf2^T bf16 [bh][80][128] ----------------
__global__ __launch_bounds__(256) void reduce_final_kernel(
    const float* __restrict__ pkv, const float* __restrict__ pkm,
    ushort* __restrict__ Kt)
{
  const int bh = blockIdx.x, t = threadIdx.x;
  const float inv_n = 1.f / (float)NPOS;
  for (int i = t; i < 8192; i += 256) {
    float s = 0.f;
    #pragma unroll
    for (int sp = 0; sp < RSPLIT; sp++) s += pkv[((size_t)(sp*128 + bh) << 13) + i];
    const int d = i >> 6, e = i & 63;
    const int dd = (e < 32) ? d : (d ^ 1);
    Kt[((size_t)bh*80 + e)*128 + dd] = f2bf(s * inv_n);
  }
  if (t < 128) {
    float s = 0.f;
    #pragma unroll
    for (int sp = 0; sp < RSPLIT; sp++) s += pkm[((size_t)(sp*128 + bh) << 7) + t];
    const ushort b = f2bf(s * inv_n);
    Kt[((size_t)bh*80 + 64)*128 + t] = b;          // km (denom_sim column)
    Kt[((size_t)bh*80 + 65)*128 + (t ^ 1)] = b;    // km swapped (denom_opp)
  }
  for (int i = t; i < 14*128; i += 256) Kt[((size_t)bh*80 + 66)*128 + i] = 0;
}

// ---------------- attention apply: MFMA [128x80] = QS[128x128] @ Kt^T -------
__global__ __launch_bounds__(256) void attn_mfma_kernel(
    const ushort* __restrict__ QS, const ushort* __restrict__ Kt,
    ushort* __restrict__ XO)
{
  __shared__ ushort qs_s[128*128];
  __shared__ ushort kv_s[80*128];
  const int t = threadIdx.x, wave = t >> 6, lane = t & 63;
  const int bh = blockIdx.y;
  const int n0 = blockIdx.x * 128;

  const ushort* ksrc = Kt + (size_t)bh * 80 * 128;
  #pragma unroll
  for (int j = 0; j < 5; j++) {
    const int elem = (j*4096 + wave*1024) >> 1;
    glds16(ksrc + elem + lane*8, kv_s + elem);
  }
  const ushort* qsrc = QS + ((size_t)bh * NPOS + n0) * 128;
  #pragma unroll
  for (int j = 0; j < 8; j++) {
    const int elem = (j*4096 + wave*1024) >> 1;
    glds16(qsrc + elem + lane*8, qs_s + elem);
  }
  __syncthreads();

  const int lm = lane & 15, q8 = (lane >> 4) * 8;
  float4v acc[2][5];
  #pragma unroll
  for (int i = 0; i < 2; i++)
    #pragma unroll
    for (int j = 0; j < 5; j++) { float4v z = {0.f,0.f,0.f,0.f}; acc[i][j] = z; }

  #pragma unroll
  for (int ks = 0; ks < 4; ks++) {
    short8v a[2], b[5];
    #pragma unroll
    for (int i = 0; i < 2; i++)
      a[i] = *(const short8v*)&qs_s[(wave*32 + i*16 + lm)*128 + ks*32 + q8];
    #pragma unroll
    for (int j = 0; j < 5; j++)
      b[j] = *(const short8v*)&kv_s[(j*16 + lm)*128 + ks*32 + q8];
    #pragma unroll
    for (int i = 0; i < 2; i++)
      #pragma unroll
      for (int j = 0; j < 5; j++)
        acc[i][j] = mfma16(a[i], b[j], acc[i][j]);
  }

  const int rq = (lane >> 4) * 4;
  #pragma unroll
  for (int i = 0; i < 2; i++) {
    #pragma unroll
    for (int r = 0; r < 4; r++) {
      const int n = n0 + wave*32 + i*16 + rq + r;
      const float dsim = __shfl(acc[i][4][r], lane & 48);
      const float dopp = __shfl(acc[i][4][r], (lane & 48) | 1);
      const float zs = 1.f / (dsim + 1e-6f);
      const float zo = 1.f / (dopp + 1e-6f);
      if (n < NPOS) {
        ushort* orow = XO + (((size_t)bh * NPOS + n) << 6);
        #pragma unroll
        for (int j = 0; j < 4; j++)
          orow[j*16 + lm] = f2bf(acc[i][j][r] * ((j < 2) ? zs : zo));
      }
    }
  }
}

// ------- 5x5 depthwise conv (Vt image-major, vector staging) + combine -------
__global__ __launch_bounds__(256) void conv_combine_kernel(
    const ushort* __restrict__ Vt, const ushort* __restrict__ XO,
    const ushort* __restrict__ g, const float* __restrict__ dwc_w,
    const float* __restrict__ dwc_b, ushort* __restrict__ cmb)
{
  __shared__ ushort vs[6*60*66];   // 47520 B -> 3 blocks/CU
  const int t = threadIdx.x;
  const int bh = blockIdx.y, b = bh >> 3, h = bh & 7;
  const int y0 = blockIdx.x * 2;

  // zero the x-halo columns xs in {0,1,58,59}
  for (int i = t; i < 6*64*4; i += 256) {
    const int c = i & 63, rem = i >> 6;       // rem 0..23
    const int ry = rem >> 2, hs = rem & 3;
    const int xs = (hs < 2) ? hs : hs + 56;   // 0,1,58,59
    vs[(ry*60 + xs)*66 + c] = 0;
  }
  // octet loads: 6 ry x 64 c x 7 j (j fastest for x-contiguous coalescing)
  for (int i = t; i < 6*64*7; i += 256) {
    const int j = i % 7;
    const int rem = i / 7;
    const int c = rem & 63, ry = rem >> 6;
    const int yy = y0 - 2 + ry;
    const int base = (ry*60 + j*8 + 2)*66 + c;
    if (yy >= 0 && yy < 56) {
      short8v v = *(const short8v*)&Vt[((size_t)bh*64 + c)*NPOS + yy*56 + j*8];
      #pragma unroll
      for (int e = 0; e < 8; e++) vs[base + e*66] = (ushort)v[e];
    } else {
      #pragma unroll
      for (int e = 0; e < 8; e++) vs[base + e*66] = 0;
    }
  }
  __syncthreads();

  const int c = t & 63, xg = t >> 6;   // 4 x-groups of 14
  float w[25];
  #pragma unroll
  for (int i = 0; i < 25; i++) w[i] = dwc_w[c*25 + i];
  const float bias = dwc_b[c];

  float acc[2][14];
  #pragma unroll
  for (int y = 0; y < 2; y++)
    #pragma unroll
    for (int xi = 0; xi < 14; xi++) acc[y][xi] = bias;

  #pragma unroll
  for (int r = 0; r < 6; r++) {
    float rv[18];
    const ushort* row = &vs[(r*60 + xg*14)*66 + c];
    #pragma unroll
    for (int xl = 0; xl < 18; xl++) rv[xl] = bf2f(row[xl*66]);
    #pragma unroll
    for (int y = 0; y < 2; y++) {
      const int ky = r - y;
      if (ky >= 0 && ky < 5) {
        #pragma unroll
        for (int xl = 0; xl < 18; xl++) {
          #pragma unroll
          for (int kx = 0; kx < 5; kx++) {
            const int xi = xl - kx;
            if (xi >= 0 && xi < 14)
              acc[y][xi] = fmaf(w[ky*5 + kx], rv[xl], acc[y][xi]);
          }
        }
      }
    }
  }

  #pragma unroll
  for (int y = 0; y < 2; y++) {
    const int yo = y0 + y;
    #pragma unroll
    for (int xi = 0; xi < 14; xi++) {
      const int n = yo*56 + xg*14 + xi;
      const float xov = bf2f(XO[(((size_t)bh*NPOS + n) << 6) + c]);
      const size_t nat = ((size_t)b*NPOS + n)*512 + h*64 + c;
      cmb[nat] = f2bf((xov + acc[y][xi]) * bf2f(g[nat]));
    }
  }
}

// ---------------- launch ----------------
extern "C" void kernel_launch(void* const* d_in, const int* in_sizes, int n_in,
                              void* d_out, int out_size, void* d_ws, size_t ws_size,
                              hipStream_t stream)
{
  const float* x       = (const float*)d_in[0];
  const float* qg_w    = (const float*)d_in[1];
  const float* kv_w    = (const float*)d_in[2];
  const float* proj_w  = (const float*)d_in[3];
  const float* proj_b  = (const float*)d_in[4];
  const float* pos_enc = (const float*)d_in[5];
  const float* scale_p = (const float*)d_in[6];
  const float* power_p = (const float*)d_in[7];
  const float* dwc_w   = (const float*)d_in[8];
  const float* dwc_b   = (const float*)d_in[9];
  float* out = (float*)d_out;

  const size_t MCs = (size_t)MROWS * 512;        // 25,690,112
  ushort* xbf = (ushort*)d_ws;                   // x bf16 -> later XO bf16 head-major
  ushort* KQ  = xbf + MCs;                       // KFt [128][128][3136] -> QS -> cmb
  ushort* Vt  = KQ + 2*MCs + 8192;               // v^T bf16 [128bh][64e][3136]
  ushort* Kt  = Vt + MCs;                        // kvf2^T bf16 [128][80][128]
  ushort* wqg = Kt + (size_t)128*80*128;         // qg_w^T bf16 [1024][512]
  ushort* wkv = wqg + (size_t)1024*512;
  ushort* wpj = wkv + (size_t)1024*512;          // proj_w^T bf16 [512][512]
  float* pkv  = (float*)(wpj + (size_t)512*512); // 7*128*8192
  float* pkm  = pkv + (size_t)RSPLIT*128*8192;   // 7*128*128
  float* scinv= pkm + (size_t)RSPLIT*128*128;
  float* pwr  = scinv + 512;
  const size_t need = (size_t)((char*)(pwr + 512) - (char*)d_ws);
  if (ws_size < need) return;

  ushort* XOb = xbf;          // aliases x_bf (dead after qg GEMM)
  ushort* cmb = KQ;           // aliases QS (dead after attn)
  ushort* gbuf = (ushort*)out;// g bf16 in d_out low half (consumed before proj overwrites)
  float* peT = (float*)d_out + 13000000;  // pos_enc^T fp32 [512][3136] scratch
                                          // (d_out = 25.69M f32; gbuf = first 12.85M f32)

  prep_kernel<<<1, 512, 0, stream>>>(scale_p, power_p, scinv, pwr);
  cvt_x_kernel<<<(int)(MCs/4/256), 256, 0, stream>>>(x, xbf);
  transpose_w_kernel<<<dim3(32,16), 256, 0, stream>>>(qg_w,   wqg, 512, 1024);
  transpose_w_kernel<<<dim3(32,16), 256, 0, stream>>>(kv_w,   wkv, 512, 1024);
  transpose_w_kernel<<<dim3(16,16), 256, 0, stream>>>(proj_w, wpj, 512, 512);
  transpose_pe_kernel<<<dim3(16,98), 256, 0, stream>>>(pos_enc, peT);

  // kv GEMM, transposed orientation: A=wkv (M=1024), B=xbf (N'=50176)
  gemm_bf16_kernel<<<dim3(8, MROWS/128), 512, 0, stream>>>(
      wkv, xbf, 3, scinv, pwr, peT, nullptr, nullptr, KQ, Vt, 3);
  reduce_kv_kernel<<<dim3(RSPLIT, 128), 256, 0, stream>>>(KQ, Vt, pkv, pkm);
  reduce_final_kernel<<<128, 256, 0, stream>>>(pkv, pkm, Kt);
  // qg GEMM: QS features + g bf16 (into d_out)
  gemm_bf16_kernel<<<dim3(8, MROWS/128), 512, 0, stream>>>(
      xbf, wqg, 0, scinv, pwr, nullptr, nullptr, nullptr, KQ, gbuf, 3);
  attn_mfma_kernel<<<dim3(25, 128), 256, 0, stream>>>(KQ, Kt, XOb);
  conv_combine_kernel<<<dim3(28, 128), 256, 0, stream>>>(Vt, XOb, gbuf, dwc_w, dwc_b, cmb);
  // proj GEMM (N=512 -> nbx_shift=2, grid 4x392)
  gemm_bf16_kernel<<<dim3(4, MROWS/128), 512, 0, stream>>>(
      cmb, wpj, 2, nullptr, nullptr, nullptr, proj_b, out, nullptr, nullptr, 2);
}

// Round 8
// 615.356 us; speedup vs baseline: 1.0901x; 1.0340x over previous
//
#include <hip/hip_runtime.h>
#include <math.h>

typedef unsigned short ushort;
typedef __attribute__((ext_vector_type(8))) short short8v;
typedef __attribute__((ext_vector_type(4))) short short4v;
typedef __attribute__((ext_vector_type(4))) float float4v;
typedef __attribute__((ext_vector_type(8))) __bf16 bf16x8;

#define NHEADS 8
#define NPOS 3136
#define MROWS 50176          // 16*3136
#define KDIM 512

__device__ __forceinline__ ushort f2bf(float f) {
  union { float f; unsigned u; } x; x.f = f;
  unsigned r = x.u + 0x7fffu + ((x.u >> 16) & 1u);
  return (ushort)(r >> 16);
}
__device__ __forceinline__ float bf2f(ushort h) {
  union { unsigned u; float f; } x; x.u = ((unsigned)h) << 16; return x.f;
}

__device__ __forceinline__ float4v mfma16(short8v a, short8v b, float4v c) {
  return __builtin_amdgcn_mfma_f32_16x16x32_bf16(
      __builtin_bit_cast(bf16x8, a), __builtin_bit_cast(bf16x8, b), c, 0, 0, 0);
}

__device__ __forceinline__ void glds16(const void* g, void* l) {
  __builtin_amdgcn_global_load_lds(
      (const __attribute__((address_space(1))) unsigned int*)g,
      (__attribute__((address_space(3))) unsigned int*)l, 16, 0, 0);
}

// fast 2^x / log2(x) (single VOP1, ~1 ulp — inputs are bf16-derived)
__device__ __forceinline__ float fexp2(float x) {
  float r; asm("v_exp_f32 %0, %1" : "=v"(r) : "v"(x)); return r;
}
__device__ __forceinline__ float flog2(float x) {
  float r; asm("v_log_f32 %0, %1" : "=v"(r) : "v"(x)); return r;
}

// ---------------- prep: scale_inv, power ----------------
__global__ __launch_bounds__(512) void prep_kernel(const float* __restrict__ scale_p,
                                                   const float* __restrict__ power_p,
                                                   float* __restrict__ scinv,
                                                   float* __restrict__ pwr)
{
  int t = threadIdx.x;
  if (t < KDIM) {
    scinv[t] = 1.f / log1pf(expf(scale_p[t]));
    pwr[t]   = 1.f + 4.f / (1.f + expf(-power_p[t]));
  }
}

// ---------------- x fp32 -> bf16 ----------------
__global__ __launch_bounds__(256) void cvt_x_kernel(const float* __restrict__ x,
                                                    ushort* __restrict__ xb)
{
  const size_t i = ((size_t)blockIdx.x * 256 + threadIdx.x) * 4;
  float4v v = *(const float4v*)(x + i);
  short4v o = { (short)f2bf(v[0]), (short)f2bf(v[1]), (short)f2bf(v[2]), (short)f2bf(v[3]) };
  *(short4v*)(xb + i) = o;
}

// ---------------- weight transpose fp32[K][N] -> bf16[N][K] ----------------
__global__ __launch_bounds__(256) void transpose_w_kernel(const float* __restrict__ src,
                                                          ushort* __restrict__ dst,
                                                          int K, int N)
{
  __shared__ float tile[32][33];
  const int t = threadIdx.x, tx = t & 31, ty = t >> 5;
  const int nb = blockIdx.x * 32, kb = blockIdx.y * 32;
  #pragma unroll
  for (int i = 0; i < 4; i++)
    tile[ty + i*8][tx] = src[(size_t)(kb + ty + i*8) * N + nb + tx];
  __syncthreads();
  #pragma unroll
  for (int i = 0; i < 4; i++)
    dst[(size_t)(nb + ty + i*8) * K + kb + tx] = f2bf(tile[tx][ty + i*8]);
}

// ---------------- pos_enc transpose fp32[3136][512] -> fp32[512][3136] -------
__global__ __launch_bounds__(256) void transpose_pe_kernel(const float* __restrict__ src,
                                                           float* __restrict__ dst)
{
  __shared__ float tile[32][33];
  const int t = threadIdx.x, tx = t & 31, ty = t >> 5;
  const int nb = blockIdx.x * 32, kb = blockIdx.y * 32;   // nb over 512, kb over 3136
  #pragma unroll
  for (int i = 0; i < 4; i++)
    tile[ty + i*8][tx] = src[(size_t)(kb + ty + i*8) * 512 + nb + tx];
  __syncthreads();
  #pragma unroll
  for (int i = 0; i < 4; i++)
    dst[(size_t)(nb + ty + i*8) * NPOS + kb + tx] = tile[tx][ty + i*8];
}

// ------- bf16 MFMA GEMM 128x128xK512, 3-deep ring + counted vmcnt -------
// Round-5 config (proven fastest): 8 waves (2M x 4N), wave tile 64x32, BK=32,
// ring-3 = 48 KiB -> 3 blocks/CU, prefetch distance 2 via s_waitcnt vmcnt(2),
// setprio(1) around the MFMA cluster (measured 125->122 us).
// mode 0: qg (A=xbf, Bt=wqg): QS interleaved features + g natural
// mode 2: proj: natural fp32 + bias
// mode 3: kv TRANSPOSED orientation (A=wkv, Bt=xbf): KFt [bh][128f][3136]
//         (f=2d+neg) and Vt [bh][64e][3136]; pos_enc arg = peT fp32 [512][3136].
__global__ __launch_bounds__(512, 6) void gemm_bf16_kernel(
    const ushort* __restrict__ A, const ushort* __restrict__ Bt, int mode,
    const float* __restrict__ scinv, const float* __restrict__ pwr,
    const float* __restrict__ pos_enc, const float* __restrict__ bias,
    float* __restrict__ outf, ushort* __restrict__ outb0, ushort* __restrict__ outb1,
    int nbx_shift)
{
  __shared__ ushort As[3][128*32];   // 3 x 8 KiB
  __shared__ ushort Bs[3][128*32];   // 3 x 8 KiB
  const int t = threadIdx.x;
  const int wave = t >> 6, lane = t & 63;

  // bijective chunked XCD swizzle (nwg divisible by 8)
  const int nwg = (int)(gridDim.x * gridDim.y);
  const int lid = (int)(blockIdx.y * gridDim.x + blockIdx.x);
  const int nlid = (lid & 7) * (nwg >> 3) + (lid >> 3);
  const int bx = nlid & ((1 << nbx_shift) - 1);
  const int by = nlid >> nbx_shift;
  const int m0 = ((mode == 3) ? bx : by) * 128;
  const int n0 = ((mode == 3) ? by : bx) * 128;

  const int wm = wave >> 2, wn = wave & 3;      // wave tile: 64 rows x 32 cols
  const int lm = lane & 15, q = lane >> 4;

  // ---- staging addressing: thread t -> row t>>2, phys chunk t&3 ----
  const int srow = t >> 2;
  const int lc = ((t & 3) ^ (srow & 3) ^ ((srow >> 2) & 3)) * 8;  // logical chunk (shorts)
  const ushort* gA = A  + (size_t)(m0 + srow) * KDIM + lc;
  const ushort* gB = Bt + (size_t)(n0 + srow) * KDIM + lc;

  // ---- read addressing: phys chunk = q ^ (lm&3) ^ ((lm>>2)&3) ----
  const int pc = (q ^ (lm & 3) ^ ((lm >> 2) & 3)) * 8;
  const int arow = wm * 64 + lm;
  const int brow = wn * 32 + lm;

  float4v acc[4][2];
  #pragma unroll
  for (int i = 0; i < 4; i++)
    #pragma unroll
    for (int j = 0; j < 2; j++) { float4v z = {0.f,0.f,0.f,0.f}; acc[i][j] = z; }

  // prologue: stage tiles 0 and 1
  glds16(gA,      &As[0][t*8]);
  glds16(gB,      &Bs[0][t*8]);
  glds16(gA + 32, &As[1][t*8]);
  glds16(gB + 32, &Bs[1][t*8]);

  #pragma unroll
  for (int kt = 0; kt < 16; kt++) {
    // wait for stage kt (2 newer glds of stage kt+1 may stay in flight)
    if (kt < 15) asm volatile("s_waitcnt vmcnt(2)" ::: "memory");
    else         asm volatile("s_waitcnt vmcnt(0)" ::: "memory");
    __builtin_amdgcn_sched_barrier(0);
    __builtin_amdgcn_s_barrier();
    if (kt + 2 < 16) {
      const int nb = (kt + 2) % 3;   // == buf of stage kt-1: reads done pre-barrier
      glds16(gA + (kt + 2) * 32, &As[nb][t*8]);
      glds16(gB + (kt + 2) * 32, &Bs[nb][t*8]);
    }
    const int cb = kt % 3;
    short8v a[4], b[2];
    #pragma unroll
    for (int i = 0; i < 4; i++)
      a[i] = *(const short8v*)&As[cb][(arow + i*16) * 32 + pc];
    #pragma unroll
    for (int j = 0; j < 2; j++)
      b[j] = *(const short8v*)&Bs[cb][(brow + j*16) * 32 + pc];
    __builtin_amdgcn_s_setprio(1);
    #pragma unroll
    for (int i = 0; i < 4; i++)
      #pragma unroll
      for (int j = 0; j < 2; j++)
        acc[i][j] = mfma16(a[i], b[j], acc[i][j]);
    __builtin_amdgcn_s_setprio(0);
  }

  // ---------------- epilogue ----------------
  const int rq = (lane >> 4) * 4;
  if (mode == 3) {
    #pragma unroll
    for (int i = 0; i < 4; i++) {
      const int of0 = m0 + wm * 64 + i * 16 + rq;
      #pragma unroll
      for (int j = 0; j < 2; j++) {
        const int gn = n0 + wn * 32 + j * 16;   // 16-aligned; 3136%16==0 -> no straddle
        const int bb = gn / NPOS;
        const int nn = gn - bb * NPOS + lm;
        #pragma unroll
        for (int r = 0; r < 4; r++) {
          const int o = of0 + r;
          const float val = acc[i][j][r];
          if (o < 512) {
            const int h = o >> 6, d = o & 63;
            const float sv = (val + pos_enc[(size_t)o * NPOS + nn]) * scinv[o];
            const float pw = pwr[o];
            const float aq = fabsf(sv);
            const float f = fexp2(pw * flog2(aq));   // aq=0 -> 0
            const ushort fb = f2bf(f);
            ushort* kr = outb0 + ((size_t)((bb << 3) + h) * 128 + 2 * d) * NPOS + nn;
            kr[0]    = (sv > 0.f) ? fb : (ushort)0;
            kr[NPOS] = (sv < 0.f) ? fb : (ushort)0;
          } else {
            const int ov = o - 512;
            const int h = ov >> 6, e = ov & 63;
            outb1[((size_t)((bb << 3) + h) * 64 + e) * NPOS + nn] = f2bf(val);
          }
        }
      }
    }
  } else {
    #pragma unroll
    for (int i = 0; i < 4; i++) {
      #pragma unroll
      for (int r = 0; r < 4; r++) {
        const int grow = m0 + wm * 64 + i * 16 + rq + r;
        const int bb = grow / NPOS;
        const int nn = grow - bb * NPOS;
        #pragma unroll
        for (int j = 0; j < 2; j++) {
          const int gcol = n0 + wn * 32 + j * 16 + lm;
          const float val = acc[i][j][r];
          if (mode == 2) {
            outf[(size_t)grow * 512 + gcol] = val + bias[gcol];
          } else if (gcol < 512) {
            const float sv = val * scinv[gcol];
            const float pw = pwr[gcol];
            const float aq = fabsf(sv);
            const float f = fexp2(pw * flog2(aq));
            const unsigned fb = (unsigned)f2bf(f);
            unsigned pack = 0;
            if (sv > 0.f)      pack = fb;
            else if (sv < 0.f) pack = fb << 16;
            const int h = gcol >> 6, d = gcol & 63;
            unsigned* qrow = (unsigned*)(outb0 + (((size_t)((bb << 3) + h) * NPOS + nn) << 7));
            qrow[d] = pack;   // features interleaved: f=2d (pos), 2d+1 (neg)
          } else {
            const int c2 = gcol - 512;
            outb1[(size_t)grow * 512 + c2] = f2bf(val);        // g bf16 natural
          }
        }
      }
    }
  }
}

// ------- kv reduce as MFMA GEMM: pkv[sp][bh][128f][64e] = KFt·Vt^T ---------
// A = KFt [bh][128f][3136], B = Vt [bh][64e][3136], contraction over n.
// Per block: M=128, N=64, K=448 (RSPLIT=7). 4 waves (2x2), wave tile 64x32.
// km (row-sums of KFt) via constant ones-column B fragment -> pkm.
// (no setprio here: 4-wave near-lockstep = the T5-hurts regime, m190)
#define RSPLIT 7
#define RK 448
__global__ __launch_bounds__(256, 4) void reduce_kv_kernel(
    const ushort* __restrict__ KFt, const ushort* __restrict__ Vt,
    float* __restrict__ pkv, float* __restrict__ pkm)
{
  __shared__ ushort As[3][128*32];   // 3 x 8 KiB
  __shared__ ushort Bs[3][64*32];    // 3 x 4 KiB
  const int sp = blockIdx.x, bh = blockIdx.y;
  const int t = threadIdx.x;
  const int wave = t >> 6, lane = t & 63;
  const int wm = wave >> 1, wn = wave & 1;
  const int lm = lane & 15, q = lane >> 4;

  const int r0 = t >> 2;
  const int lc = ((t & 3) ^ (r0 & 3) ^ ((r0 >> 2) & 3)) * 8;
  const ushort* gA = KFt + ((size_t)bh * 128 + r0) * NPOS + sp * RK + lc;  // rows 0..63 (+64 via offset)
  const ushort* gB = Vt  + ((size_t)bh * 64  + r0) * NPOS + sp * RK + lc;
  const size_t A64 = (size_t)64 * NPOS;   // swizzle identical for row+64

  const int pc = (q ^ (lm & 3) ^ ((lm >> 2) & 3)) * 8;
  const int arow = wm * 64 + lm;
  const int brow = wn * 32 + lm;

  float4v acc[4][2], accK[4];
  #pragma unroll
  for (int i = 0; i < 4; i++) {
    #pragma unroll
    for (int j = 0; j < 2; j++) { float4v z = {0.f,0.f,0.f,0.f}; acc[i][j] = z; }
    float4v z = {0.f,0.f,0.f,0.f}; accK[i] = z;
  }
  short8v bk;
  #pragma unroll
  for (int c = 0; c < 8; c++) bk[c] = (short)((lm == 0) ? 0x3F80 : 0);

  // prologue: stage tiles 0 and 1
  glds16(gA,            &As[0][t*8]);
  glds16(gA + A64,      &As[0][2048 + t*8]);
  glds16(gB,            &Bs[0][t*8]);
  glds16(gA + 32,       &As[1][t*8]);
  glds16(gA + A64 + 32, &As[1][2048 + t*8]);
  glds16(gB + 32,       &Bs[1][t*8]);

  #pragma unroll
  for (int kt = 0; kt < 14; kt++) {
    if (kt < 13) asm volatile("s_waitcnt vmcnt(3)" ::: "memory");
    else         asm volatile("s_waitcnt vmcnt(0)" ::: "memory");
    __builtin_amdgcn_sched_barrier(0);
    __builtin_amdgcn_s_barrier();
    if (kt + 2 < 14) {
      const int nb = (kt + 2) % 3;
      const int off = (kt + 2) * 32;
      glds16(gA + off,       &As[nb][t*8]);
      glds16(gA + A64 + off, &As[nb][2048 + t*8]);
      glds16(gB + off,       &Bs[nb][t*8]);
    }
    const int cb = kt % 3;
    short8v a[4], b[2];
    #pragma unroll
    for (int i = 0; i < 4; i++)
      a[i] = *(const short8v*)&As[cb][(arow + i*16) * 32 + pc];
    #pragma unroll
    for (int j = 0; j < 2; j++)
      b[j] = *(const short8v*)&Bs[cb][(brow + j*16) * 32 + pc];
    #pragma unroll
    for (int i = 0; i < 4; i++)
      #pragma unroll
      for (int j = 0; j < 2; j++)
        acc[i][j] = mfma16(a[i], b[j], acc[i][j]);
    if (wn == 0) {
      #pragma unroll
      for (int i = 0; i < 4; i++)
        accK[i] = mfma16(a[i], bk, accK[i]);
    }
  }

  const int rq = q * 4;
  float* op = pkv + (((size_t)sp * 128 + bh) << 13);
  #pragma unroll
  for (int i = 0; i < 4; i++)
    #pragma unroll
    for (int j = 0; j < 2; j++)
      #pragma unroll
      for (int r = 0; r < 4; r++)
        op[(size_t)(wm*64 + i*16 + rq + r) * 64 + wn*32 + j*16 + lm] = acc[i][j][r];
  if (wn == 0 && lm == 0) {
    float* kp = pkm + (((size_t)sp * 128 + bh) << 7);
    #pragma unroll
    for (int i = 0; i < 4; i++)
      #pragma unroll
      for (int r = 0; r < 4; r++)
        kp[wm*64 + i*16 + rq + r] = accK[i][r];
  }
}

// ---------------- final reduce -> kvf2^T bf16 [bh][80][128] ----------------
__global__ __launch_bounds__(256) void reduce_final_kernel(
    const float* __restrict__ pkv, const float* __restrict__ pkm,
    ushort* __restrict__ Kt)
{
  const int bh = blockIdx.x, t = threadIdx.x;
  const float inv_n = 1.f / (float)NPOS;
  for (int i = t; i < 8192; i += 256) {
    float s = 0.f;
    #pragma unroll
    for (int sp = 0; sp < RSPLIT; sp++) s += pkv[((size_t)(sp*128 + bh) << 13) + i];
    const int d = i >> 6, e = i & 63;
    const int dd = (e < 32) ? d : (d ^ 1);
    Kt[((size_t)bh*80 + e)*128 + dd] = f2bf(s * inv_n);
  }
  if (t < 128) {
    float s = 0.f;
    #pragma unroll
    for (int sp = 0; sp < RSPLIT; sp++) s += pkm[((size_t)(sp*128 + bh) << 7) + t];
    const ushort b = f2bf(s * inv_n);
    Kt[((size_t)bh*80 + 64)*128 + t] = b;          // km (denom_sim column)
    Kt[((size_t)bh*80 + 65)*128 + (t ^ 1)] = b;    // km swapped (denom_opp)
  }
  for (int i = t; i < 14*128; i += 256) Kt[((size_t)bh*80 + 66)*128 + i] = 0;
}

// ---------------- attention apply: MFMA [128x80] = QS[128x128] @ Kt^T -------
__global__ __launch_bounds__(256) void attn_mfma_kernel(
    const ushort* __restrict__ QS, const ushort* __restrict__ Kt,
    ushort* __restrict__ XO)
{
  __shared__ ushort qs_s[128*128];
  __shared__ ushort kv_s[80*128];
  const int t = threadIdx.x, wave = t >> 6, lane = t & 63;
  const int bh = blockIdx.y;
  const int n0 = blockIdx.x * 128;

  const ushort* ksrc = Kt + (size_t)bh * 80 * 128;
  #pragma unroll
  for (int j = 0; j < 5; j++) {
    const int elem = (j*4096 + wave*1024) >> 1;
    glds16(ksrc + elem + lane*8, kv_s + elem);
  }
  const ushort* qsrc = QS + ((size_t)bh * NPOS + n0) * 128;
  #pragma unroll
  for (int j = 0; j < 8; j++) {
    const int elem = (j*4096 + wave*1024) >> 1;
    glds16(qsrc + elem + lane*8, qs_s + elem);
  }
  __syncthreads();

  const int lm = lane & 15, q8 = (lane >> 4) * 8;
  float4v acc[2][5];
  #pragma unroll
  for (int i = 0; i < 2; i++)
    #pragma unroll
    for (int j = 0; j < 5; j++) { float4v z = {0.f,0.f,0.f,0.f}; acc[i][j] = z; }

  #pragma unroll
  for (int ks = 0; ks < 4; ks++) {
    short8v a[2], b[5];
    #pragma unroll
    for (int i = 0; i < 2; i++)
      a[i] = *(const short8v*)&qs_s[(wave*32 + i*16 + lm)*128 + ks*32 + q8];
    #pragma unroll
    for (int j = 0; j < 5; j++)
      b[j] = *(const short8v*)&kv_s[(j*16 + lm)*128 + ks*32 + q8];
    #pragma unroll
    for (int i = 0; i < 2; i++)
      #pragma unroll
      for (int j = 0; j < 5; j++)
        acc[i][j] = mfma16(a[i], b[j], acc[i][j]);
  }

  const int rq = (lane >> 4) * 4;
  #pragma unroll
  for (int i = 0; i < 2; i++) {
    #pragma unroll
    for (int r = 0; r < 4; r++) {
      const int n = n0 + wave*32 + i*16 + rq + r;
      const float dsim = __shfl(acc[i][4][r], lane & 48);
      const float dopp = __shfl(acc[i][4][r], (lane & 48) | 1);
      const float zs = 1.f / (dsim + 1e-6f);
      const float zo = 1.f / (dopp + 1e-6f);
      if (n < NPOS) {
        ushort* orow = XO + (((size_t)bh * NPOS + n) << 6);
        #pragma unroll
        for (int j = 0; j < 4; j++)
          orow[j*16 + lm] = f2bf(acc[i][j][r] * ((j < 2) ? zs : zo));
      }
    }
  }
}

// ------- 5x5 depthwise conv (Vt image-major) + (xo+vd)*g -> cmb -------
// Staging transposes x-major global rows into c-major LDS with 4-channel
// packed ds_write_b64: per group load 4 octets (c0..c0+3, same row/x-chunk,
// coalesced 16B) and write 8 x short4v. Stride 68 u16 (136 B) keeps every
// b64 write 8B-aligned and compute reads conflict-free (2 lanes/word).
__global__ __launch_bounds__(256) void conv_combine_kernel(
    const ushort* __restrict__ Vt, const ushort* __restrict__ XO,
    const ushort* __restrict__ g, const float* __restrict__ dwc_w,
    const float* __restrict__ dwc_b, ushort* __restrict__ cmb)
{
  __shared__ ushort vs[6*60*68];   // 48960 B -> 3 blocks/CU; [ry*60+xs][c]
  const int t = threadIdx.x;
  const int bh = blockIdx.y, b = bh >> 3, h = bh & 7;
  const int y0 = blockIdx.x * 2;

  // zero the x-halo columns xs in {0,1,58,59}
  for (int i = t; i < 6*64*4; i += 256) {
    const int c = i & 63, rem = i >> 6;       // rem 0..23
    const int ry = rem >> 2, hs = rem & 3;
    const int xs = (hs < 2) ? hs : hs + 56;   // 0,1,58,59
    vs[(ry*60 + xs)*68 + c] = 0;
  }
  // staging: 672 groups = (ry 0..5) x (cg 0..15) x (j 0..6), j fastest
  for (int idx = t; idx < 672; idx += 256) {
    const int cgry = idx / 7;                 // const-div -> magic mul
    const int j = idx - cgry * 7;
    const int ry = cgry >> 4, c0 = (cgry & 15) * 4;
    const int yy = y0 - 2 + ry;
    short8v v0 = {0,0,0,0,0,0,0,0}, v1 = v0, v2 = v0, v3 = v0;
    if (yy >= 0 && yy < 56) {
      const ushort* src = &Vt[((size_t)bh*64 + c0)*NPOS + yy*56 + j*8];
      v0 = *(const short8v*)(src);
      v1 = *(const short8v*)(src + NPOS);
      v2 = *(const short8v*)(src + 2*NPOS);
      v3 = *(const short8v*)(src + 3*NPOS);
    }
    ushort* dst = &vs[(ry*60 + j*8 + 2)*68 + c0];
    #pragma unroll
    for (int e = 0; e < 8; e++) {
      short4v p = { v0[e], v1[e], v2[e], v3[e] };
      *(short4v*)(dst + e*68) = p;
    }
  }
  __syncthreads();

  const int c = t & 63, xg = t >> 6;   // 4 x-groups of 14
  float w[25];
  #pragma unroll
  for (int i = 0; i < 25; i++) w[i] = dwc_w[c*25 + i];
  const float bias = dwc_b[c];

  float acc[2][14];
  #pragma unroll
  for (int y = 0; y < 2; y++)
    #pragma unroll
    for (int xi = 0; xi < 14; xi++) acc[y][xi] = bias;

  #pragma unroll
  for (int r = 0; r < 6; r++) {
    float rv[18];
    const ushort* row = &vs[(r*60 + xg*14)*68 + c];
    #pragma unroll
    for (int xl = 0; xl < 18; xl++) rv[xl] = bf2f(row[xl*68]);
    #pragma unroll
    for (int y = 0; y < 2; y++) {
      const int ky = r - y;
      if (ky >= 0 && ky < 5) {
        #pragma unroll
        for (int xl = 0; xl < 18; xl++) {
          #pragma unroll
          for (int kx = 0; kx < 5; kx++) {
            const int xi = xl - kx;
            if (xi >= 0 && xi < 14)
              acc[y][xi] = fmaf(w[ky*5 + kx], rv[xl], acc[y][xi]);
          }
        }
      }
    }
  }

  #pragma unroll
  for (int y = 0; y < 2; y++) {
    const int yo = y0 + y;
    #pragma unroll
    for (int xi = 0; xi < 14; xi++) {
      const int n = yo*56 + xg*14 + xi;
      const float xov = bf2f(XO[(((size_t)bh*NPOS + n) << 6) + c]);
      const size_t nat = ((size_t)b*NPOS + n)*512 + h*64 + c;
      cmb[nat] = f2bf((xov + acc[y][xi]) * bf2f(g[nat]));
    }
  }
}

// ---------------- launch ----------------
extern "C" void kernel_launch(void* const* d_in, const int* in_sizes, int n_in,
                              void* d_out, int out_size, void* d_ws, size_t ws_size,
                              hipStream_t stream)
{
  const float* x       = (const float*)d_in[0];
  const float* qg_w    = (const float*)d_in[1];
  const float* kv_w    = (const float*)d_in[2];
  const float* proj_w  = (const float*)d_in[3];
  const float* proj_b  = (const float*)d_in[4];
  const float* pos_enc = (const float*)d_in[5];
  const float* scale_p = (const float*)d_in[6];
  const float* power_p = (const float*)d_in[7];
  const float* dwc_w   = (const float*)d_in[8];
  const float* dwc_b   = (const float*)d_in[9];
  float* out = (float*)d_out;

  const size_t MCs = (size_t)MROWS * 512;        // 25,690,112
  ushort* xbf = (ushort*)d_ws;                   // x bf16 -> later XO bf16 head-major
  ushort* KQ  = xbf + MCs;                       // KFt [128][128][3136] -> QS -> cmb
  ushort* Vt  = KQ + 2*MCs + 8192;               // v^T bf16 [128bh][64e][3136]
  ushort* Kt  = Vt + MCs;                        // kvf2^T bf16 [128][80][128]
  ushort* wqg = Kt + (size_t)128*80*128;         // qg_w^T bf16 [1024][512]
  ushort* wkv = wqg + (size_t)1024*512;
  ushort* wpj = wkv + (size_t)1024*512;          // proj_w^T bf16 [512][512]
  float* pkv  = (float*)(wpj + (size_t)512*512); // 7*128*8192
  float* pkm  = pkv + (size_t)RSPLIT*128*8192;   // 7*128*128
  float* scinv= pkm + (size_t)RSPLIT*128*128;
  float* pwr  = scinv + 512;
  const size_t need = (size_t)((char*)(pwr + 512) - (char*)d_ws);
  if (ws_size < need) return;

  ushort* XOb = xbf;          // aliases x_bf (dead after qg GEMM)
  ushort* cmb = KQ;           // aliases QS (dead after attn)
  ushort* gbuf = (ushort*)out;// g bf16 in d_out low half (consumed before proj overwrites)
  float* peT = (float*)d_out + 13000000;  // pos_enc^T fp32 [512][3136] scratch
                                          // (d_out = 25.69M f32; gbuf = first 12.85M f32)

  prep_kernel<<<1, 512, 0, stream>>>(scale_p, power_p, scinv, pwr);
  cvt_x_kernel<<<(int)(MCs/4/256), 256, 0, stream>>>(x, xbf);
  transpose_w_kernel<<<dim3(32,16), 256, 0, stream>>>(qg_w,   wqg, 512, 1024);
  transpose_w_kernel<<<dim3(32,16), 256, 0, stream>>>(kv_w,   wkv, 512, 1024);
  transpose_w_kernel<<<dim3(16,16), 256, 0, stream>>>(proj_w, wpj, 512, 512);
  transpose_pe_kernel<<<dim3(16,98), 256, 0, stream>>>(pos_enc, peT);

  // kv GEMM, transposed orientation: A=wkv (M=1024), B=xbf (N'=50176)
  gemm_bf16_kernel<<<dim3(8, MROWS/128), 512, 0, stream>>>(
      wkv, xbf, 3, scinv, pwr, peT, nullptr, nullptr, KQ, Vt, 3);
  reduce_kv_kernel<<<dim3(RSPLIT, 128), 256, 0, stream>>>(KQ, Vt, pkv, pkm);
  reduce_final_kernel<<<128, 256, 0, stream>>>(pkv, pkm, Kt);
  // qg GEMM: QS features + g bf16 (into d_out)
  gemm_bf16_kernel<<<dim3(8, MROWS/128), 512, 0, stream>>>(
      xbf, wqg, 0, scinv, pwr, nullptr, nullptr, nullptr, KQ, gbuf, 3);
  attn_mfma_kernel<<<dim3(25, 128), 256, 0, stream>>>(KQ, Kt, XOb);
  conv_combine_kernel<<<dim3(28, 128), 256, 0, stream>>>(Vt, XOb, gbuf, dwc_w, dwc_b, cmb);
  // proj GEMM (N=512 -> nbx_shift=2, grid 4x392)
  gemm_bf16_kernel<<<dim3(4, MROWS/128), 512, 0, stream>>>(
      cmb, wpj, 2, nullptr, nullptr, nullptr, proj_b, out, nullptr, nullptr, 2);
}